// Round 1
// baseline (657.610 us; speedup 1.0000x reference)
//
#include <hip/hip_runtime.h>

typedef unsigned short ushort_t;
typedef __attribute__((ext_vector_type(4))) float f32x4;
typedef __attribute__((ext_vector_type(8))) short s16x8;

#define SB 8388608   // x batch stride (512*16*32*32)
#define SC 16384     // x channel stride (16*32*32)
#define SF 1024      // x frame stride (32*32)

static __device__ __forceinline__ float bf2f(ushort_t u) {
    union { float f; unsigned int i; } x; x.i = ((unsigned int)u) << 16; return x.f;
}
static __device__ __forceinline__ ushort_t f2bf(float f) {
    union { float f; unsigned int i; } x; x.f = f;
    unsigned int u = x.i;
    unsigned int r = (u + 0x7FFFu + ((u >> 16) & 1u)) >> 16;
    return (ushort_t)r;
}

// ---------------- K0: convert weights to bf16 ----------------
__global__ void k_cvt(const float* __restrict__ a, int n1,
                      const float* __restrict__ b, int n2,
                      ushort_t* __restrict__ o1, ushort_t* __restrict__ o2) {
    int i = blockIdx.x * blockDim.x + threadIdx.x;
    if (i < n1) o1[i] = f2bf(a[i]);
    if (i < n2) o2[i] = f2bf(b[i]);
}

// ---------------- K1: LayerNorm + transpose -> xn (65536 x 512) bf16 ----------------
// block = (b, f, h); loads x[b, :, f, h, :] tile (512 c x 32 w), LN over c per w.
__global__ __launch_bounds__(256) void k_ln_transpose(
        const float* __restrict__ x, const float* __restrict__ g,
        const float* __restrict__ bta, ushort_t* __restrict__ xn) {
    __shared__ float tile[32 * 513];
    __shared__ float gg[512];
    __shared__ float bb[512];
    int bid = blockIdx.x;
    int b = bid >> 9;
    int f = (bid >> 5) & 15;
    int h = bid & 31;
    int t = threadIdx.x;
    for (int c = t; c < 512; c += 256) { gg[c] = g[c]; bb[c] = bta[c]; }
    const float* xp = x + (size_t)b * SB + (size_t)f * SF + h * 32;
    int w = t & 31;
    int c0 = t >> 5;  // 8 c-rows per iteration
    for (int it = 0; it < 64; ++it) {
        int c = c0 + it * 8;
        tile[w * 513 + c] = xp[(size_t)c * SC + w];
    }
    __syncthreads();
    int lane = t & 63;
    int wave = t >> 6;
    for (int wi = 0; wi < 8; ++wi) {
        int ww = wave * 8 + wi;
        float s = 0.f, s2 = 0.f;
        #pragma unroll
        for (int j = 0; j < 8; ++j) {
            float v = tile[ww * 513 + lane + j * 64];
            s += v; s2 += v * v;
        }
        #pragma unroll
        for (int off = 32; off; off >>= 1) { s += __shfl_xor(s, off); s2 += __shfl_xor(s2, off); }
        float mean = s * (1.f / 512.f);
        float var = s2 * (1.f / 512.f) - mean * mean;
        float rstd = rsqrtf(var + 1e-5f);
        size_t row = ((size_t)((b * 32 + h) * 32 + ww)) * 16 + f;
        ushort_t* op = xn + row * 512 + lane * 8;
        union { ushort_t a[8]; s16x8 v; } u;
        #pragma unroll
        for (int j = 0; j < 8; ++j) {
            int c = lane * 8 + j;
            float v = tile[ww * 513 + c];
            u.a[j] = f2bf((v - mean) * rstd * gg[c] + bb[c]);
        }
        *(s16x8*)op = u.v;
    }
}

// ---------------- K2: fused QKV GEMM + attention ----------------
// block = 2 sequences (32 rows of xn), 512 threads (8 waves).
// Phase 1: qkv(32x1536) = xn_tile(32x512) @ Wqkv^T, staged bf16 in LDS.
// Phase 2: per-(seq,head) attention in registers, write att (65536x512) bf16.
__global__ __launch_bounds__(512) void k_qkv_attn(
        const ushort_t* __restrict__ xn, const ushort_t* __restrict__ wq,
        const float* __restrict__ rb, ushort_t* __restrict__ att) {
    __shared__ ushort_t xT[32 * 520];
    __shared__ ushort_t kT[32 * 1544];
    int t = threadIdx.x;
    int bid = blockIdx.x;
    int m0 = bid * 32;
    // stage xn tile
    {
        int row = t >> 4;
        int c0 = (t & 15) * 32;
        const ushort_t* src = xn + (size_t)(m0 + row) * 512 + c0;
        ushort_t* dst = xT + row * 520 + c0;
        #pragma unroll
        for (int u = 0; u < 4; ++u)
            *(s16x8*)(dst + u * 8) = *(const s16x8*)(src + u * 8);
    }
    __syncthreads();
    int lane = t & 63;
    int wv = t >> 6;
    int l16 = lane & 15;
    int lg = lane >> 4;
    // GEMM: wave wv owns cols [wv*192, wv*192+192), in 3 groups of 64
    for (int g3 = 0; g3 < 3; ++g3) {
        int nb0 = wv * 192 + g3 * 64;
        f32x4 acc[2][4];
        #pragma unroll
        for (int m = 0; m < 2; ++m)
            #pragma unroll
            for (int nb = 0; nb < 4; ++nb)
                acc[m][nb] = (f32x4){0.f, 0.f, 0.f, 0.f};
        for (int ks = 0; ks < 16; ++ks) {
            int k = ks * 32 + lg * 8;
            s16x8 a0 = *(const s16x8*)(xT + l16 * 520 + k);
            s16x8 a1 = *(const s16x8*)(xT + (16 + l16) * 520 + k);
            #pragma unroll
            for (int nb = 0; nb < 4; ++nb) {
                int n = nb0 + nb * 16 + l16;
                s16x8 bf = *(const s16x8*)(wq + (size_t)n * 512 + k);
                acc[0][nb] = __builtin_amdgcn_mfma_f32_16x16x32_bf16(a0, bf, acc[0][nb], 0, 0, 0);
                acc[1][nb] = __builtin_amdgcn_mfma_f32_16x16x32_bf16(a1, bf, acc[1][nb], 0, 0, 0);
            }
        }
        #pragma unroll
        for (int m = 0; m < 2; ++m)
            #pragma unroll
            for (int nb = 0; nb < 4; ++nb) {
                int col = nb0 + nb * 16 + l16;
                int rbase = m * 16 + lg * 4;
                #pragma unroll
                for (int r = 0; r < 4; ++r)
                    kT[(rbase + r) * 1544 + col] = f2bf(acc[m][nb][r]);
            }
    }
    __syncthreads();
    // attention: 16 (seq,head) pairs, 2 per wave
    for (int pp = 0; pp < 2; ++pp) {
        int pair = wv + pp * 8;
        int s = pair >> 3;
        int hd = pair & 7;
        int i = l16;
        int p = lg;
        const ushort_t* qrow = kT + (s * 16 + i) * 1544 + hd * 64 + p * 16;
        float qf[16];
        {
            s16x8 q0 = *(const s16x8*)qrow;
            s16x8 q1 = *(const s16x8*)(qrow + 8);
            #pragma unroll
            for (int d = 0; d < 8; ++d) { qf[d] = bf2f((ushort_t)q0[d]); qf[8 + d] = bf2f((ushort_t)q1[d]); }
        }
        float sc[16];
        #pragma unroll
        for (int j = 0; j < 16; ++j) {
            const ushort_t* krow = kT + (s * 16 + j) * 1544 + 512 + hd * 64 + p * 16;
            s16x8 k0 = *(const s16x8*)krow;
            s16x8 k1 = *(const s16x8*)(krow + 8);
            float a = 0.f;
            #pragma unroll
            for (int d = 0; d < 8; ++d) a += qf[d] * bf2f((ushort_t)k0[d]);
            #pragma unroll
            for (int d = 0; d < 8; ++d) a += qf[8 + d] * bf2f((ushort_t)k1[d]);
            sc[j] = a;
        }
        #pragma unroll
        for (int j = 0; j < 16; ++j) {
            float v = sc[j];
            v += __shfl_xor(v, 16);
            v += __shfl_xor(v, 32);
            sc[j] = v * 0.125f + rb[i * 64 + j];
        }
        float mx = sc[0];
        #pragma unroll
        for (int j = 1; j < 16; ++j) mx = fmaxf(mx, sc[j]);
        float sum = 0.f;
        #pragma unroll
        for (int j = 0; j < 16; ++j) { sc[j] = __expf(sc[j] - mx); sum += sc[j]; }
        float inv = 1.f / sum;
        float o[16];
        #pragma unroll
        for (int d = 0; d < 16; ++d) o[d] = 0.f;
        #pragma unroll
        for (int j = 0; j < 16; ++j) {
            float pj = sc[j] * inv;
            const ushort_t* vrow = kT + (s * 16 + j) * 1544 + 1024 + hd * 64 + p * 16;
            s16x8 v0 = *(const s16x8*)vrow;
            s16x8 v1 = *(const s16x8*)(vrow + 8);
            #pragma unroll
            for (int d = 0; d < 8; ++d) { o[d] += pj * bf2f((ushort_t)v0[d]); o[8 + d] += pj * bf2f((ushort_t)v1[d]); }
        }
        ushort_t* op = att + (size_t)(m0 + s * 16 + i) * 512 + hd * 64 + p * 16;
        union { ushort_t a[8]; s16x8 v; } u0, u1;
        #pragma unroll
        for (int d = 0; d < 8; ++d) { u0.a[d] = f2bf(o[d]); u1.a[d] = f2bf(o[8 + d]); }
        *(s16x8*)op = u0.v;
        *(s16x8*)(op + 8) = u1.v;
    }
}

// ---------------- K3: proj GEMM + bias + residual + transpose-out ----------------
// block = (b, f, h): 32 rows (all w), N=512, K=512. 512 threads (8 waves).
__global__ __launch_bounds__(512) void k_proj_out(
        const ushort_t* __restrict__ att, const ushort_t* __restrict__ wp,
        const float* __restrict__ bp, const float* __restrict__ x,
        float* __restrict__ out) {
    __shared__ ushort_t aT[32 * 520];
    __shared__ float oT[32 * 516];
    int bid = blockIdx.x;
    int b = bid >> 9;
    int f = (bid >> 5) & 15;
    int h = bid & 31;
    int t = threadIdx.x;
    {
        int w = t >> 4;
        int c0 = (t & 15) * 32;
        size_t row = ((size_t)((b * 32 + h) * 32 + w)) * 16 + f;
        const ushort_t* src = att + row * 512 + c0;
        ushort_t* dst = aT + w * 520 + c0;
        #pragma unroll
        for (int u = 0; u < 4; ++u)
            *(s16x8*)(dst + u * 8) = *(const s16x8*)(src + u * 8);
    }
    __syncthreads();
    int lane = t & 63;
    int wv = t >> 6;
    int l16 = lane & 15;
    int lg = lane >> 4;
    int nb0 = wv * 64;
    f32x4 acc[2][4];
    #pragma unroll
    for (int m = 0; m < 2; ++m)
        #pragma unroll
        for (int nb = 0; nb < 4; ++nb)
            acc[m][nb] = (f32x4){0.f, 0.f, 0.f, 0.f};
    for (int ks = 0; ks < 16; ++ks) {
        int k = ks * 32 + lg * 8;
        s16x8 a0 = *(const s16x8*)(aT + l16 * 520 + k);
        s16x8 a1 = *(const s16x8*)(aT + (16 + l16) * 520 + k);
        #pragma unroll
        for (int nb = 0; nb < 4; ++nb) {
            int n = nb0 + nb * 16 + l16;
            s16x8 bf = *(const s16x8*)(wp + (size_t)n * 512 + k);
            acc[0][nb] = __builtin_amdgcn_mfma_f32_16x16x32_bf16(a0, bf, acc[0][nb], 0, 0, 0);
            acc[1][nb] = __builtin_amdgcn_mfma_f32_16x16x32_bf16(a1, bf, acc[1][nb], 0, 0, 0);
        }
    }
    #pragma unroll
    for (int m = 0; m < 2; ++m)
        #pragma unroll
        for (int nb = 0; nb < 4; ++nb) {
            int col = nb0 + nb * 16 + l16;
            int rbase = m * 16 + lg * 4;
            #pragma unroll
            for (int r = 0; r < 4; ++r)
                oT[(rbase + r) * 516 + col] = acc[m][nb][r];
        }
    __syncthreads();
    const float* xp = x + (size_t)b * SB + (size_t)f * SF + h * 32;
    float* op = out + (size_t)b * SB + (size_t)f * SF + h * 32;
    int w = t & 31;
    int cbase = t >> 5;  // 16 c-values per pass
    for (int it = 0; it < 32; ++it) {
        int c = cbase + it * 16;
        float v = oT[w * 516 + c] + bp[c] + xp[(size_t)c * SC + w];
        op[(size_t)c * SC + w] = v;
    }
}

extern "C" void kernel_launch(void* const* d_in, const int* in_sizes, int n_in,
                              void* d_out, int out_size, void* d_ws, size_t ws_size,
                              hipStream_t stream) {
    const float* x     = (const float*)d_in[0];
    const float* wqkv  = (const float*)d_in[1];
    const float* wproj = (const float*)d_in[2];
    const float* bproj = (const float*)d_in[3];
    const float* rb    = (const float*)d_in[4];
    const float* lng   = (const float*)d_in[5];
    const float* lnb   = (const float*)d_in[6];
    float* out = (float*)d_out;
    char* ws = (char*)d_ws;
    ushort_t* xn   = (ushort_t*)(ws);                  // 65536*512*2 = 64 MB
    ushort_t* att  = (ushort_t*)(ws + 67108864);       // 64 MB
    ushort_t* wq16 = (ushort_t*)(ws + 134217728);      // 1.5 MB
    ushort_t* wp16 = (ushort_t*)(ws + 135790592);      // 0.5 MB

    k_cvt<<<3072, 256, 0, stream>>>(wqkv, 1536 * 512, wproj, 512 * 512, wq16, wp16);
    k_ln_transpose<<<2048, 256, 0, stream>>>(x, lng, lnb, xn);
    k_qkv_attn<<<2048, 512, 0, stream>>>(xn, wq16, rb, att);
    k_proj_out<<<2048, 512, 0, stream>>>(att, wp16, bproj, x, out);
}

// Round 2
// 415.693 us; speedup vs baseline: 1.5820x; 1.5820x over previous
//
#include <hip/hip_runtime.h>

typedef unsigned short ushort_t;
typedef __attribute__((ext_vector_type(4))) float f32x4;
typedef __attribute__((ext_vector_type(8))) short s16x8;
typedef __attribute__((ext_vector_type(4))) short s16x4;

#define SB 8388608   // x batch stride (512*16*32*32)
#define SC 16384     // x channel stride (16*32*32)
#define SF 1024      // x frame stride (32*32)

static __device__ __forceinline__ float bf2f(ushort_t u) {
    union { float f; unsigned int i; } x; x.i = ((unsigned int)u) << 16; return x.f;
}
static __device__ __forceinline__ ushort_t f2bf(float f) {
    union { float f; unsigned int i; } x; x.f = f;
    unsigned int u = x.i;
    unsigned int r = (u + 0x7FFFu + ((u >> 16) & 1u)) >> 16;
    return (ushort_t)r;
}

static __device__ __forceinline__ void gload16(const void* g, void* l) {
    __builtin_amdgcn_global_load_lds(
        (const __attribute__((address_space(1))) unsigned int*)g,
        (__attribute__((address_space(3))) unsigned int*)l, 16, 0, 0);
}

// ---------------- K0: convert weights to bf16 ----------------
__global__ void k_cvt(const float* __restrict__ a, int n1,
                      const float* __restrict__ b, int n2,
                      ushort_t* __restrict__ o1, ushort_t* __restrict__ o2) {
    int i = blockIdx.x * blockDim.x + threadIdx.x;
    if (i < n1) o1[i] = f2bf(a[i]);
    if (i < n2) o2[i] = f2bf(b[i]);
}

// ---------------- K1: LayerNorm + transpose -> xn (65536 x 512) bf16 ----------------
__global__ __launch_bounds__(256) void k_ln_transpose(
        const float* __restrict__ x, const float* __restrict__ g,
        const float* __restrict__ bta, ushort_t* __restrict__ xn) {
    __shared__ float tile[32 * 513];
    __shared__ float gg[512];
    __shared__ float bb[512];
    int bid = blockIdx.x;
    int b = bid >> 9;
    int f = (bid >> 5) & 15;
    int h = bid & 31;
    int t = threadIdx.x;
    for (int c = t; c < 512; c += 256) { gg[c] = g[c]; bb[c] = bta[c]; }
    const float* xp = x + (size_t)b * SB + (size_t)f * SF + h * 32;
    int w = t & 31;
    int c0 = t >> 5;
    for (int it = 0; it < 64; ++it) {
        int c = c0 + it * 8;
        tile[w * 513 + c] = xp[(size_t)c * SC + w];
    }
    __syncthreads();
    int lane = t & 63;
    int wave = t >> 6;
    for (int wi = 0; wi < 8; ++wi) {
        int ww = wave * 8 + wi;
        float s = 0.f, s2 = 0.f;
        #pragma unroll
        for (int j = 0; j < 8; ++j) {
            float v = tile[ww * 513 + lane + j * 64];
            s += v; s2 += v * v;
        }
        #pragma unroll
        for (int off = 32; off; off >>= 1) { s += __shfl_xor(s, off); s2 += __shfl_xor(s2, off); }
        float mean = s * (1.f / 512.f);
        float var = s2 * (1.f / 512.f) - mean * mean;
        float rstd = rsqrtf(var + 1e-5f);
        size_t row = ((size_t)((b * 32 + h) * 32 + ww)) * 16 + f;
        ushort_t* op = xn + row * 512 + lane * 8;
        union { ushort_t a[8]; s16x8 v; } u;
        #pragma unroll
        for (int j = 0; j < 8; ++j) {
            int c = lane * 8 + j;
            float v = tile[ww * 513 + c];
            u.a[j] = f2bf((v - mean) * rstd * gg[c] + bb[c]);
        }
        *(s16x8*)op = u.v;
    }
}

// ---------------- K2: fused QKV GEMM + attention (rewritten) ----------------
// block = 8 sequences (128 rows), 512 threads (8 waves). Per head h:
//   GEMM: qkv_h(128x192) = A(128x512) @ B_h(192x512)^T, double-buffered LDS,
//         global_load_lds staging with pre-swizzled source (T2/G21).
//   Attention: per wave one seq; S = mfma(K,Q) (swapped), softmax in-reg,
//         P relayout via LDS, PV = mfma(P, V^T) with V stored transposed.
__global__ __launch_bounds__(512, 2) void k_qkv_attn(
        const ushort_t* __restrict__ xn, const ushort_t* __restrict__ wq,
        const float* __restrict__ rb, ushort_t* __restrict__ att) {
    __shared__ ushort_t Ab[2][128 * 64];   // A K-slice, dbuf (32 KB)
    __shared__ ushort_t Bb[2][192 * 64];   // B K-slice, dbuf (48 KB)
    __shared__ ushort_t qsm[128 * 64];     // Q chunk, XOR-swizzled (16 KB)
    __shared__ ushort_t ksm[128 * 64];     // K chunk, XOR-swizzled (16 KB)
    __shared__ ushort_t vT[64 * 136];      // V^T chunk [d][m], padded (17 KB)
    __shared__ ushort_t ps[8 * 256];       // per-wave P 16x16 (4 KB)

    const int t = threadIdx.x;
    const int lane = t & 63;
    const int wv = t >> 6;
    const int l16 = lane & 15;
    const int lg = lane >> 4;
    const int m0 = blockIdx.x * 128;
    const int wm = wv >> 2;   // 0..1  (M half)
    const int wn = wv & 3;    // 0..3  (N quarter)

    // stage A K-slice kb into buffer buf (source pre-swizzled so linear LDS
    // dest + XOR-swizzled read are conflict-free)
    auto stageA = [&](int buf, int kb) {
        #pragma unroll
        for (int it = 0; it < 2; ++it) {
            int f = t + it * 512;          // 16B unit, 0..1023
            int row = f >> 3, slot = f & 7;
            const ushort_t* src = xn + (size_t)(m0 + row) * 512 + kb * 64 + ((slot ^ (row & 7)) << 3);
            gload16(src, &Ab[buf][f * 8]);
        }
    };
    auto stageB = [&](int buf, int kb, int h) {
        #pragma unroll
        for (int it = 0; it < 3; ++it) {
            int f = t + it * 512;          // 0..1535
            int brow = f >> 3, slot = f & 7;
            int seg = brow >> 6;           // 0=q,1=k,2=v
            int wrow = seg * 512 + h * 64 + (brow & 63);
            const ushort_t* src = wq + (size_t)wrow * 512 + kb * 64 + ((slot ^ (brow & 7)) << 3);
            gload16(src, &Bb[buf][f * 8]);
        }
    };

    stageA(0, 0); stageB(0, 0, 0);
    __syncthreads();

    for (int h = 0; h < 8; ++h) {
        f32x4 acc[4][3];
        #pragma unroll
        for (int a1 = 0; a1 < 4; ++a1)
            #pragma unroll
            for (int a2 = 0; a2 < 3; ++a2)
                acc[a1][a2] = (f32x4){0.f, 0.f, 0.f, 0.f};

        int cur = 0;
        for (int kb = 0; kb < 8; ++kb) {
            if (kb < 7) { stageA(cur ^ 1, kb + 1); stageB(cur ^ 1, kb + 1, h); }
            #pragma unroll
            for (int kk = 0; kk < 2; ++kk) {
                int koff = kk * 64 + lg * 16;   // byte offset within 128B row
                s16x8 af[4], bf[3];
                #pragma unroll
                for (int mf = 0; mf < 4; ++mf) {
                    int row = wm * 64 + mf * 16 + l16;
                    af[mf] = *(const s16x8*)&Ab[cur][row * 64 + ((koff ^ ((row & 7) << 4)) >> 1)];
                }
                #pragma unroll
                for (int nf = 0; nf < 3; ++nf) {
                    int nrow = wn * 48 + nf * 16 + l16;
                    bf[nf] = *(const s16x8*)&Bb[cur][nrow * 64 + ((koff ^ ((nrow & 7) << 4)) >> 1)];
                }
                #pragma unroll
                for (int mf = 0; mf < 4; ++mf)
                    #pragma unroll
                    for (int nf = 0; nf < 3; ++nf)
                        acc[mf][nf] = __builtin_amdgcn_mfma_f32_16x16x32_bf16(af[mf], bf[nf], acc[mf][nf], 0, 0, 0);
            }
            __syncthreads();
            cur ^= 1;
        }

        // C-write: q/k swizzled [m][d], V transposed [d][m]
        #pragma unroll
        for (int mf = 0; mf < 4; ++mf) {
            int mbase = wm * 64 + mf * 16 + lg * 4;
            #pragma unroll
            for (int nf = 0; nf < 3; ++nf) {
                int nn = wn * 48 + nf * 16 + l16;
                int seg = nn >> 6;
                int d = nn & 63;
                if (seg == 2) {
                    union { s16x4 v; ushort_t a[4]; } pk;
                    #pragma unroll
                    for (int r = 0; r < 4; ++r) pk.a[r] = f2bf(acc[mf][nf][r]);
                    *(s16x4*)&vT[d * 136 + mbase] = pk.v;
                } else {
                    ushort_t* dst = seg ? ksm : qsm;
                    #pragma unroll
                    for (int r = 0; r < 4; ++r) {
                        int m = mbase + r;
                        dst[m * 64 + (d ^ ((m & 7) << 3))] = f2bf(acc[mf][nf][r]);
                    }
                }
            }
        }
        __syncthreads();

        // ---- attention: wave wv handles sequence wv (16 rows) ----
        {
            int arow = wv * 16 + l16;
            int sw = (arow & 7) << 4;
            f32x4 sacc = (f32x4){0.f, 0.f, 0.f, 0.f};
            #pragma unroll
            for (int kk = 0; kk < 2; ++kk) {
                int off = kk * 64 + lg * 16;
                s16x8 ka = *(const s16x8*)&ksm[arow * 64 + ((off ^ sw) >> 1)];
                s16x8 qb = *(const s16x8*)&qsm[arow * 64 + ((off ^ sw) >> 1)];
                sacc = __builtin_amdgcn_mfma_f32_16x16x32_bf16(ka, qb, sacc, 0, 0, 0);
            }
            // lane holds S[j][i]: i = l16, j = lg*4+r
            const float* rbp = rb + l16 * 64 + lg * 4;
            float p[4];
            float mx = -1e30f;
            #pragma unroll
            for (int r = 0; r < 4; ++r) {
                p[r] = sacc[r] * 0.125f + rbp[r];
                mx = fmaxf(mx, p[r]);
            }
            mx = fmaxf(mx, __shfl_xor(mx, 16));
            mx = fmaxf(mx, __shfl_xor(mx, 32));
            float sum = 0.f;
            #pragma unroll
            for (int r = 0; r < 4; ++r) { p[r] = __expf(p[r] - mx); sum += p[r]; }
            sum += __shfl_xor(sum, 16);
            sum += __shfl_xor(sum, 32);
            float inv = 1.f / sum;
            {
                union { s16x4 v; ushort_t a[4]; } pk;
                #pragma unroll
                for (int r = 0; r < 4; ++r) pk.a[r] = f2bf(p[r] * inv);
                *(s16x4*)&ps[wv * 256 + l16 * 16 + lg * 4] = pk.v;   // P[i][j]
            }
            asm volatile("s_waitcnt lgkmcnt(0)" ::: "memory");
            // PV: A = P rows i (j padded to 32 with zeros), B = vT rows d
            s16x8 ap = (s16x8){0, 0, 0, 0, 0, 0, 0, 0};
            if (lg < 2) ap = *(const s16x8*)&ps[wv * 256 + l16 * 16 + lg * 8];
            int jj = (lg < 2) ? lg * 8 : 0;
            f32x4 ov[4];
            #pragma unroll
            for (int ff = 0; ff < 4; ++ff) {
                int d = ff * 16 + l16;
                s16x8 bv = *(const s16x8*)&vT[d * 136 + wv * 16 + jj];
                ov[ff] = __builtin_amdgcn_mfma_f32_16x16x32_bf16(ap, bv, (f32x4){0.f, 0.f, 0.f, 0.f}, 0, 0, 0);
            }
            // stage output through LDS (reuse Bb[1]) for coalesced 16B stores
            ushort_t* ol = (ushort_t*)Bb[1];
            #pragma unroll
            for (int ff = 0; ff < 4; ++ff)
                #pragma unroll
                for (int r = 0; r < 4; ++r)
                    ol[wv * 1024 + (lg * 4 + r) * 64 + ff * 16 + l16] = f2bf(ov[ff][r]);
            asm volatile("s_waitcnt lgkmcnt(0)" ::: "memory");
            {
                int i2 = lane >> 2;
                int c2 = (lane & 3) * 16;
                s16x8 w0 = *(const s16x8*)&ol[wv * 1024 + i2 * 64 + c2];
                s16x8 w1 = *(const s16x8*)&ol[wv * 1024 + i2 * 64 + c2 + 8];
                ushort_t* op = att + (size_t)(m0 + wv * 16 + i2) * 512 + h * 64 + c2;
                *(s16x8*)op = w0;
                *(s16x8*)(op + 8) = w1;
            }
        }
        if (h < 7) { stageA(0, 0); stageB(0, 0, h + 1); }
        __syncthreads();
    }
}

// ---------------- K3: proj GEMM + bias + residual + transpose-out ----------------
__global__ __launch_bounds__(512) void k_proj_out(
        const ushort_t* __restrict__ att, const ushort_t* __restrict__ wp,
        const float* __restrict__ bp, const float* __restrict__ x,
        float* __restrict__ out) {
    __shared__ ushort_t aT[32 * 520];
    __shared__ float oT[32 * 516];
    int bid = blockIdx.x;
    int b = bid >> 9;
    int f = (bid >> 5) & 15;
    int h = bid & 31;
    int t = threadIdx.x;
    {
        int w = t >> 4;
        int c0 = (t & 15) * 32;
        size_t row = ((size_t)((b * 32 + h) * 32 + w)) * 16 + f;
        const ushort_t* src = att + row * 512 + c0;
        ushort_t* dst = aT + w * 520 + c0;
        #pragma unroll
        for (int u = 0; u < 4; ++u)
            *(s16x8*)(dst + u * 8) = *(const s16x8*)(src + u * 8);
    }
    __syncthreads();
    int lane = t & 63;
    int wv = t >> 6;
    int l16 = lane & 15;
    int lg = lane >> 4;
    int nb0 = wv * 64;
    f32x4 acc[2][4];
    #pragma unroll
    for (int m = 0; m < 2; ++m)
        #pragma unroll
        for (int nb = 0; nb < 4; ++nb)
            acc[m][nb] = (f32x4){0.f, 0.f, 0.f, 0.f};
    for (int ks = 0; ks < 16; ++ks) {
        int k = ks * 32 + lg * 8;
        s16x8 a0 = *(const s16x8*)(aT + l16 * 520 + k);
        s16x8 a1 = *(const s16x8*)(aT + (16 + l16) * 520 + k);
        #pragma unroll
        for (int nb = 0; nb < 4; ++nb) {
            int n = nb0 + nb * 16 + l16;
            s16x8 bf = *(const s16x8*)(wp + (size_t)n * 512 + k);
            acc[0][nb] = __builtin_amdgcn_mfma_f32_16x16x32_bf16(a0, bf, acc[0][nb], 0, 0, 0);
            acc[1][nb] = __builtin_amdgcn_mfma_f32_16x16x32_bf16(a1, bf, acc[1][nb], 0, 0, 0);
        }
    }
    #pragma unroll
    for (int m = 0; m < 2; ++m)
        #pragma unroll
        for (int nb = 0; nb < 4; ++nb) {
            int col = nb0 + nb * 16 + l16;
            int rbase = m * 16 + lg * 4;
            #pragma unroll
            for (int r = 0; r < 4; ++r)
                oT[(rbase + r) * 516 + col] = acc[m][nb][r];
        }
    __syncthreads();
    const float* xp = x + (size_t)b * SB + (size_t)f * SF + h * 32;
    float* op = out + (size_t)b * SB + (size_t)f * SF + h * 32;
    int w = t & 31;
    int cbase = t >> 5;
    for (int it = 0; it < 32; ++it) {
        int c = cbase + it * 16;
        float v = oT[w * 516 + c] + bp[c] + xp[(size_t)c * SC + w];
        op[(size_t)c * SC + w] = v;
    }
}

extern "C" void kernel_launch(void* const* d_in, const int* in_sizes, int n_in,
                              void* d_out, int out_size, void* d_ws, size_t ws_size,
                              hipStream_t stream) {
    const float* x     = (const float*)d_in[0];
    const float* wqkv  = (const float*)d_in[1];
    const float* wproj = (const float*)d_in[2];
    const float* bproj = (const float*)d_in[3];
    const float* rb    = (const float*)d_in[4];
    const float* lng   = (const float*)d_in[5];
    const float* lnb   = (const float*)d_in[6];
    float* out = (float*)d_out;
    char* ws = (char*)d_ws;
    ushort_t* xn   = (ushort_t*)(ws);                  // 64 MB
    ushort_t* att  = (ushort_t*)(ws + 67108864);       // 64 MB
    ushort_t* wq16 = (ushort_t*)(ws + 134217728);      // 1.5 MB
    ushort_t* wp16 = (ushort_t*)(ws + 135790592);      // 0.5 MB

    k_cvt<<<3072, 256, 0, stream>>>(wqkv, 1536 * 512, wproj, 512 * 512, wq16, wp16);
    k_ln_transpose<<<2048, 256, 0, stream>>>(x, lng, lnb, xn);
    k_qkv_attn<<<512, 512, 0, stream>>>(xn, wq16, rb, att);
    k_proj_out<<<2048, 512, 0, stream>>>(att, wp16, bproj, x, out);
}

// Round 4
// 365.504 us; speedup vs baseline: 1.7992x; 1.1373x over previous
//
#include <hip/hip_runtime.h>

typedef unsigned short ushort_t;
typedef __attribute__((ext_vector_type(4))) float f32x4;
typedef __attribute__((ext_vector_type(8))) short s16x8;
typedef __attribute__((ext_vector_type(4))) short s16x4;

#define SB 8388608   // x batch stride (512*16*32*32)
#define SC 16384     // x channel stride (16*32*32)
#define SF 1024      // x frame stride (32*32)

static __device__ __forceinline__ float bf2f(ushort_t u) {
    union { float f; unsigned int i; } x; x.i = ((unsigned int)u) << 16; return x.f;
}
static __device__ __forceinline__ ushort_t f2bf(float f) {
    union { float f; unsigned int i; } x; x.f = f;
    unsigned int u = x.i;
    unsigned int r = (u + 0x7FFFu + ((u >> 16) & 1u)) >> 16;
    return (ushort_t)r;
}

static __device__ __forceinline__ void gload16(const void* g, void* l) {
    __builtin_amdgcn_global_load_lds(
        (const __attribute__((address_space(1))) unsigned int*)g,
        (__attribute__((address_space(3))) unsigned int*)l, 16, 0, 0);
}

// ---------------- K0: convert weights to bf16 ----------------
__global__ void k_cvt(const float* __restrict__ a, int n1,
                      const float* __restrict__ b, int n2,
                      ushort_t* __restrict__ o1, ushort_t* __restrict__ o2) {
    int i = blockIdx.x * blockDim.x + threadIdx.x;
    if (i < n1) o1[i] = f2bf(a[i]);
    if (i < n2) o2[i] = f2bf(b[i]);
}

// ---------------- K1: LayerNorm + transpose -> xn (65536 x 512) bf16 ----------------
__global__ __launch_bounds__(256) void k_ln_transpose(
        const float* __restrict__ x, const float* __restrict__ g,
        const float* __restrict__ bta, ushort_t* __restrict__ xn) {
    __shared__ float tile[32 * 513];
    __shared__ float gg[512];
    __shared__ float bb[512];
    int bid = blockIdx.x;
    int b = bid >> 9;
    int f = (bid >> 5) & 15;
    int h = bid & 31;
    int t = threadIdx.x;
    for (int c = t; c < 512; c += 256) { gg[c] = g[c]; bb[c] = bta[c]; }
    const float* xp = x + (size_t)b * SB + (size_t)f * SF + h * 32;
    // vectorized load: 16 B/lane
    int wq4 = (t & 7) * 4;
    int c0 = t >> 3;
    for (int it = 0; it < 16; ++it) {
        int c = c0 + it * 32;
        f32x4 v = *(const f32x4*)(xp + (size_t)c * SC + wq4);
        tile[(wq4 + 0) * 513 + c] = v[0];
        tile[(wq4 + 1) * 513 + c] = v[1];
        tile[(wq4 + 2) * 513 + c] = v[2];
        tile[(wq4 + 3) * 513 + c] = v[3];
    }
    __syncthreads();
    int lane = t & 63;
    int wave = t >> 6;
    for (int wi = 0; wi < 8; ++wi) {
        int ww = wave * 8 + wi;
        float s = 0.f, s2 = 0.f;
        #pragma unroll
        for (int j = 0; j < 8; ++j) {
            float v = tile[ww * 513 + lane + j * 64];
            s += v; s2 += v * v;
        }
        #pragma unroll
        for (int off = 32; off; off >>= 1) { s += __shfl_xor(s, off); s2 += __shfl_xor(s2, off); }
        float mean = s * (1.f / 512.f);
        float var = s2 * (1.f / 512.f) - mean * mean;
        float rstd = rsqrtf(var + 1e-5f);
        size_t row = ((size_t)((b * 32 + h) * 32 + ww)) * 16 + f;
        ushort_t* op = xn + row * 512 + lane * 8;
        union { ushort_t a[8]; s16x8 v; } u;
        #pragma unroll
        for (int j = 0; j < 8; ++j) {
            int c = lane * 8 + j;
            float v = tile[ww * 513 + c];
            u.a[j] = f2bf((v - mean) * rstd * gg[c] + bb[c]);
        }
        *(s16x8*)op = u.v;
    }
}

// ---------------- K2: fused QKV GEMM + attention ----------------
// block = 8 sequences (128 rows), 512 threads (8 waves), LDS = 80 KB union
// (GEMM staging dbuf) U (attention buffers) -> 2 blocks/CU.
__global__ __launch_bounds__(512) void k_qkv_attn(
        const ushort_t* __restrict__ xn, const ushort_t* __restrict__ wq,
        const float* __restrict__ rb, ushort_t* __restrict__ att) {
    __shared__ __align__(16) char U[81920];
    // GEMM phase layout
    ushort_t* Ab0 = (ushort_t*)(U);            // 16384 B
    ushort_t* Ab1 = (ushort_t*)(U + 16384);    // 16384 B
    ushort_t* Bb0 = (ushort_t*)(U + 32768);    // 24576 B
    ushort_t* Bb1 = (ushort_t*)(U + 57344);    // 24576 B
    // attention phase layout (aliases the above)
    ushort_t* qsm = (ushort_t*)(U);            // 16384 B [128 m][64 d] swz
    ushort_t* ksm = (ushort_t*)(U + 16384);    // 16384 B
    ushort_t* vT  = (ushort_t*)(U + 32768);    // 17408 B [64 d][136 m]
    ushort_t* ps  = (ushort_t*)(U + 50176);    //  4096 B
    ushort_t* ol  = (ushort_t*)(U + 54272);    // 16384 B

    const int t = threadIdx.x;
    const int lane = t & 63;
    const int wv = t >> 6;
    const int l16 = lane & 15;
    const int lg = lane >> 4;
    const int m0 = blockIdx.x * 128;
    const int wm = wv >> 2;   // 0..1  (M half)
    const int wn = wv & 3;    // 0..3  (N quarter)

    auto stageA = [&](ushort_t* dst, int kb) {
        #pragma unroll
        for (int it = 0; it < 2; ++it) {
            int f = t + it * 512;          // 16B unit, 0..1023
            int row = f >> 3, slot = f & 7;
            const ushort_t* src = xn + (size_t)(m0 + row) * 512 + kb * 64 + ((slot ^ (row & 7)) << 3);
            gload16(src, dst + f * 8);
        }
    };
    auto stageB = [&](ushort_t* dst, int kb, int h) {
        #pragma unroll
        for (int it = 0; it < 3; ++it) {
            int f = t + it * 512;          // 0..1535
            int brow = f >> 3, slot = f & 7;
            int seg = brow >> 6;           // 0=q,1=k,2=v
            int wrow = seg * 512 + h * 64 + (brow & 63);
            const ushort_t* src = wq + (size_t)wrow * 512 + kb * 64 + ((slot ^ (brow & 7)) << 3);
            gload16(src, dst + f * 8);
        }
    };

    for (int h = 0; h < 8; ++h) {
        __syncthreads();                     // attn of h-1 done before re-alias
        stageA(Ab0, 0); stageB(Bb0, 0, h);
        __syncthreads();                     // staged data visible

        f32x4 acc[4][3];
        #pragma unroll
        for (int a1 = 0; a1 < 4; ++a1)
            #pragma unroll
            for (int a2 = 0; a2 < 3; ++a2)
                acc[a1][a2] = (f32x4){0.f, 0.f, 0.f, 0.f};

        int cur = 0;
        for (int kb = 0; kb < 8; ++kb) {
            ushort_t* Ac = cur ? Ab1 : Ab0;
            ushort_t* Bc = cur ? Bb1 : Bb0;
            if (kb < 7) {
                stageA(cur ? Ab0 : Ab1, kb + 1);
                stageB(cur ? Bb0 : Bb1, kb + 1, h);
            }
            #pragma unroll
            for (int kk = 0; kk < 2; ++kk) {
                int koff = kk * 64 + lg * 16;   // byte offset within 128B row
                s16x8 af[4], bf[3];
                #pragma unroll
                for (int mf = 0; mf < 4; ++mf) {
                    int row = wm * 64 + mf * 16 + l16;
                    af[mf] = *(const s16x8*)&Ac[row * 64 + ((koff ^ ((row & 7) << 4)) >> 1)];
                }
                #pragma unroll
                for (int nf = 0; nf < 3; ++nf) {
                    int nrow = wn * 48 + nf * 16 + l16;
                    bf[nf] = *(const s16x8*)&Bc[nrow * 64 + ((koff ^ ((nrow & 7) << 4)) >> 1)];
                }
                #pragma unroll
                for (int mf = 0; mf < 4; ++mf)
                    #pragma unroll
                    for (int nf = 0; nf < 3; ++nf)
                        acc[mf][nf] = __builtin_amdgcn_mfma_f32_16x16x32_bf16(af[mf], bf[nf], acc[mf][nf], 0, 0, 0);
            }
            __syncthreads();
            cur ^= 1;
        }

        // C-write: q/k swizzled [m][d], V transposed [d][m] (aliases Ab/Bb)
        #pragma unroll
        for (int mf = 0; mf < 4; ++mf) {
            int mbase = wm * 64 + mf * 16 + lg * 4;
            #pragma unroll
            for (int nf = 0; nf < 3; ++nf) {
                int nn = wn * 48 + nf * 16 + l16;
                int seg = nn >> 6;
                int d = nn & 63;
                if (seg == 2) {
                    union { s16x4 v; ushort_t a[4]; } pk;
                    #pragma unroll
                    for (int r = 0; r < 4; ++r) pk.a[r] = f2bf(acc[mf][nf][r]);
                    *(s16x4*)&vT[d * 136 + mbase] = pk.v;
                } else {
                    ushort_t* dst = seg ? ksm : qsm;
                    #pragma unroll
                    for (int r = 0; r < 4; ++r) {
                        int m = mbase + r;
                        dst[m * 64 + (d ^ ((m & 7) << 3))] = f2bf(acc[mf][nf][r]);
                    }
                }
            }
        }
        __syncthreads();

        // ---- attention: wave wv handles sequence wv (16 rows) ----
        {
            int arow = wv * 16 + l16;
            int sw = (arow & 7) << 4;
            f32x4 sacc = (f32x4){0.f, 0.f, 0.f, 0.f};
            #pragma unroll
            for (int kk = 0; kk < 2; ++kk) {
                int off = kk * 64 + lg * 16;
                s16x8 ka = *(const s16x8*)&ksm[arow * 64 + ((off ^ sw) >> 1)];
                s16x8 qb = *(const s16x8*)&qsm[arow * 64 + ((off ^ sw) >> 1)];
                sacc = __builtin_amdgcn_mfma_f32_16x16x32_bf16(ka, qb, sacc, 0, 0, 0);
            }
            // lane holds S[j][i]: i = l16, j = lg*4+r
            const float* rbp = rb + l16 * 64 + lg * 4;
            float p[4];
            float mx = -1e30f;
            #pragma unroll
            for (int r = 0; r < 4; ++r) {
                p[r] = sacc[r] * 0.125f + rbp[r];
                mx = fmaxf(mx, p[r]);
            }
            mx = fmaxf(mx, __shfl_xor(mx, 16));
            mx = fmaxf(mx, __shfl_xor(mx, 32));
            float sum = 0.f;
            #pragma unroll
            for (int r = 0; r < 4; ++r) { p[r] = __expf(p[r] - mx); sum += p[r]; }
            sum += __shfl_xor(sum, 16);
            sum += __shfl_xor(sum, 32);
            float inv = 1.f / sum;
            {
                union { s16x4 v; ushort_t a[4]; } pk;
                #pragma unroll
                for (int r = 0; r < 4; ++r) pk.a[r] = f2bf(p[r] * inv);
                *(s16x4*)&ps[wv * 256 + l16 * 16 + lg * 4] = pk.v;   // P[i][j]
            }
            asm volatile("s_waitcnt lgkmcnt(0)" ::: "memory");
            // PV: A = P rows i (j padded to 32 with zeros), B = vT rows d
            s16x8 ap = (s16x8){0, 0, 0, 0, 0, 0, 0, 0};
            if (lg < 2) ap = *(const s16x8*)&ps[wv * 256 + l16 * 16 + lg * 8];
            int jj = (lg < 2) ? lg * 8 : 0;
            f32x4 ov[4];
            #pragma unroll
            for (int ff = 0; ff < 4; ++ff) {
                int d = ff * 16 + l16;
                s16x8 bv = *(const s16x8*)&vT[d * 136 + wv * 16 + jj];
                ov[ff] = __builtin_amdgcn_mfma_f32_16x16x32_bf16(ap, bv, (f32x4){0.f, 0.f, 0.f, 0.f}, 0, 0, 0);
            }
            // stage output through LDS for coalesced 16B stores
            #pragma unroll
            for (int ff = 0; ff < 4; ++ff)
                #pragma unroll
                for (int r = 0; r < 4; ++r)
                    ol[wv * 1024 + (lg * 4 + r) * 64 + ff * 16 + l16] = f2bf(ov[ff][r]);
            asm volatile("s_waitcnt lgkmcnt(0)" ::: "memory");
            {
                int i2 = lane >> 2;
                int c2 = (lane & 3) * 16;
                s16x8 w0 = *(const s16x8*)&ol[wv * 1024 + i2 * 64 + c2];
                s16x8 w1 = *(const s16x8*)&ol[wv * 1024 + i2 * 64 + c2 + 8];
                ushort_t* op = att + (size_t)(m0 + wv * 16 + i2) * 512 + h * 64 + c2;
                *(s16x8*)op = w0;
                *(s16x8*)(op + 8) = w1;
            }
        }
    }
}

// ---------------- K3: proj GEMM + bias + residual + transpose-out ----------------
// block = (b, h, f-quad): M=128 rows (32 w x 4 f), N=512, K=512. 512 threads.
// MFMA operands: wp-frag FIRST, att-frag SECOND -> D col(l16)=M row (w),
// D row(lg*4+r)=N col (c). Epilogue stores w-coalesced.
__global__ __launch_bounds__(512) void k_proj_out(
        const ushort_t* __restrict__ att, const ushort_t* __restrict__ wp,
        const float* __restrict__ bp, const float* __restrict__ x,
        float* __restrict__ out) {
    __shared__ __align__(16) char U[81920];   // A: 2x8192, B: 2x32768
    int bid = blockIdx.x;
    int b = bid >> 7;
    int h = (bid >> 2) & 31;
    int fq = bid & 3;
    const int t = threadIdx.x;
    const int lane = t & 63;
    const int wv = t >> 6;
    const int l16 = lane & 15;
    const int lg = lane >> 4;
    const int wm = wv >> 2;   // 0..1
    const int wn = wv & 3;    // 0..3
    size_t attbase = ((size_t)(b * 32 + h) * 32) * 16 + fq * 4;  // + w*16 + fl

    auto stA = [&](int buf, int ks) {
        int u = t;                    // 512 units (128 rows x 4 slots of 16B)
        int row = u >> 2, slot = u & 3;
        int sl = slot ^ ((row >> 1) & 3);
        int w = row & 31, fl = row >> 5;
        const ushort_t* src = att + (attbase + (size_t)w * 16 + fl) * 512 + ks * 32 + sl * 8;
        gload16(src, (ushort_t*)(U + buf * 8192) + u * 8);
    };
    auto stB = [&](int buf, int ks) {
        #pragma unroll
        for (int i = 0; i < 4; ++i) {
            int u = t + i * 512;      // 2048 units (512 rows x 4 slots)
            int row = u >> 2, slot = u & 3;
            int sl = slot ^ ((row >> 1) & 3);
            const ushort_t* src = wp + (size_t)row * 512 + ks * 32 + sl * 8;
            gload16(src, (ushort_t*)(U + 16384 + buf * 32768) + u * 8);
        }
    };

    f32x4 acc[4][8];
    #pragma unroll
    for (int m = 0; m < 4; ++m)
        #pragma unroll
        for (int n = 0; n < 8; ++n)
            acc[m][n] = (f32x4){0.f, 0.f, 0.f, 0.f};

    stA(0, 0); stB(0, 0);
    __syncthreads();
    for (int ks = 0; ks < 16; ++ks) {
        int cur = ks & 1;
        if (ks < 15) { stA(cur ^ 1, ks + 1); stB(cur ^ 1, ks + 1); }
        s16x8 af[4], bf[8];
        #pragma unroll
        for (int mf = 0; mf < 4; ++mf) {
            int row = wm * 64 + mf * 16 + l16;
            af[mf] = *(const s16x8*)(U + cur * 8192 + row * 64 + ((lg ^ ((row >> 1) & 3)) << 4));
        }
        #pragma unroll
        for (int nf = 0; nf < 8; ++nf) {
            int nrow = wn * 128 + nf * 16 + l16;
            bf[nf] = *(const s16x8*)(U + 16384 + cur * 32768 + nrow * 64 + ((lg ^ ((nrow >> 1) & 3)) << 4));
        }
        #pragma unroll
        for (int mf = 0; mf < 4; ++mf)
            #pragma unroll
            for (int nf = 0; nf < 8; ++nf)
                acc[mf][nf] = __builtin_amdgcn_mfma_f32_16x16x32_bf16(bf[nf], af[mf], acc[mf][nf], 0, 0, 0);
        __syncthreads();
    }

    // epilogue: direct stores, bias + residual fused
    size_t obase = (size_t)b * SB + (size_t)(fq * 4) * SF + h * 32;
    #pragma unroll
    for (int mf = 0; mf < 4; ++mf) {
        int m = wm * 64 + mf * 16 + l16;
        int w = m & 31, fl = m >> 5;
        size_t base_m = obase + (size_t)fl * SF + w;
        #pragma unroll
        for (int nf = 0; nf < 8; ++nf) {
            int col0 = wn * 128 + nf * 16 + lg * 4;
            #pragma unroll
            for (int r = 0; r < 4; ++r) {
                int col = col0 + r;
                size_t a = base_m + (size_t)col * SC;
                out[a] = acc[mf][nf][r] + bp[col] + x[a];
            }
        }
    }
}

extern "C" void kernel_launch(void* const* d_in, const int* in_sizes, int n_in,
                              void* d_out, int out_size, void* d_ws, size_t ws_size,
                              hipStream_t stream) {
    const float* x     = (const float*)d_in[0];
    const float* wqkv  = (const float*)d_in[1];
    const float* wproj = (const float*)d_in[2];
    const float* bproj = (const float*)d_in[3];
    const float* rb    = (const float*)d_in[4];
    const float* lng   = (const float*)d_in[5];
    const float* lnb   = (const float*)d_in[6];
    float* out = (float*)d_out;
    char* ws = (char*)d_ws;
    ushort_t* xn   = (ushort_t*)(ws);                  // 64 MB
    ushort_t* att  = (ushort_t*)(ws + 67108864);       // 64 MB
    ushort_t* wq16 = (ushort_t*)(ws + 134217728);      // 1.5 MB
    ushort_t* wp16 = (ushort_t*)(ws + 135790592);      // 0.5 MB

    k_cvt<<<3072, 256, 0, stream>>>(wqkv, 1536 * 512, wproj, 512 * 512, wq16, wp16);
    k_ln_transpose<<<2048, 256, 0, stream>>>(x, lng, lnb, xn);
    k_qkv_attn<<<512, 512, 0, stream>>>(xn, wq16, rb, att);
    k_proj_out<<<512, 512, 0, stream>>>(att, wp16, bproj, x, out);
}

// Round 6
// 363.355 us; speedup vs baseline: 1.8098x; 1.0059x over previous
//
#include <hip/hip_runtime.h>

typedef unsigned short ushort_t;
typedef __attribute__((ext_vector_type(4))) float f32x4;
typedef __attribute__((ext_vector_type(8))) short s16x8;
typedef __attribute__((ext_vector_type(4))) short s16x4;

#define SB 8388608   // x batch stride (512*16*32*32)
#define SC 16384     // x channel stride (16*32*32)
#define SF 1024      // x frame stride (32*32)

static __device__ __forceinline__ float bf2f(ushort_t u) {
    union { float f; unsigned int i; } x; x.i = ((unsigned int)u) << 16; return x.f;
}
static __device__ __forceinline__ ushort_t f2bf(float f) {
    union { float f; unsigned int i; } x; x.f = f;
    unsigned int u = x.i;
    unsigned int r = (u + 0x7FFFu + ((u >> 16) & 1u)) >> 16;
    return (ushort_t)r;
}

static __device__ __forceinline__ void gload16(const void* g, void* l) {
    __builtin_amdgcn_global_load_lds(
        (const __attribute__((address_space(1))) unsigned int*)g,
        (__attribute__((address_space(3))) unsigned int*)l, 16, 0, 0);
}

// ---------------- K0: convert weights to bf16 ----------------
__global__ void k_cvt(const float* __restrict__ a, int n1,
                      const float* __restrict__ b, int n2,
                      ushort_t* __restrict__ o1, ushort_t* __restrict__ o2) {
    int i = blockIdx.x * blockDim.x + threadIdx.x;
    if (i < n1) o1[i] = f2bf(a[i]);
    if (i < n2) o2[i] = f2bf(b[i]);
}

// ---------------- K1: LayerNorm + transpose -> xn (65536 x 512) bf16 ----------------
__global__ __launch_bounds__(256) void k_ln_transpose(
        const float* __restrict__ x, const float* __restrict__ g,
        const float* __restrict__ bta, ushort_t* __restrict__ xn) {
    __shared__ float tile[32 * 513];
    __shared__ float gg[512];
    __shared__ float bb[512];
    int bid = blockIdx.x;
    int b = bid >> 9;
    int f = (bid >> 5) & 15;
    int h = bid & 31;
    int t = threadIdx.x;
    for (int c = t; c < 512; c += 256) { gg[c] = g[c]; bb[c] = bta[c]; }
    const float* xp = x + (size_t)b * SB + (size_t)f * SF + h * 32;
    int wq4 = (t & 7) * 4;
    int c0 = t >> 3;
    for (int it = 0; it < 16; ++it) {
        int c = c0 + it * 32;
        f32x4 v = *(const f32x4*)(xp + (size_t)c * SC + wq4);
        tile[(wq4 + 0) * 513 + c] = v[0];
        tile[(wq4 + 1) * 513 + c] = v[1];
        tile[(wq4 + 2) * 513 + c] = v[2];
        tile[(wq4 + 3) * 513 + c] = v[3];
    }
    __syncthreads();
    int lane = t & 63;
    int wave = t >> 6;
    for (int wi = 0; wi < 8; ++wi) {
        int ww = wave * 8 + wi;
        float s = 0.f, s2 = 0.f;
        #pragma unroll
        for (int j = 0; j < 8; ++j) {
            float v = tile[ww * 513 + lane + j * 64];
            s += v; s2 += v * v;
        }
        #pragma unroll
        for (int off = 32; off; off >>= 1) { s += __shfl_xor(s, off); s2 += __shfl_xor(s2, off); }
        float mean = s * (1.f / 512.f);
        float var = s2 * (1.f / 512.f) - mean * mean;
        float rstd = rsqrtf(var + 1e-5f);
        size_t row = ((size_t)((b * 32 + h) * 32 + ww)) * 16 + f;
        ushort_t* op = xn + row * 512 + lane * 8;
        union { ushort_t a[8]; s16x8 v; } u;
        #pragma unroll
        for (int j = 0; j < 8; ++j) {
            int c = lane * 8 + j;
            float v = tile[ww * 513 + c];
            u.a[j] = f2bf((v - mean) * rstd * gg[c] + bb[c]);
        }
        *(s16x8*)op = u.v;
    }
}

// ---------------- K2: fused QKV GEMM + attention ----------------
// block = 8 sequences (128 rows), 512 threads (8 waves). LDS = 49 KB total
// (GEMM BK=32 dbuf staging aliased under attention buffers) -> 2 blocks/CU.
__global__ __launch_bounds__(512) void k_qkv_attn(
        const ushort_t* __restrict__ xn, const ushort_t* __restrict__ wq,
        const float* __restrict__ rb, ushort_t* __restrict__ att) {
    __shared__ __align__(16) char U[50176];
    // attention layout
    ushort_t* qsm = (ushort_t*)(U);            // 16384 B [128 m][64 d] swz
    ushort_t* ksm = (ushort_t*)(U + 16384);    // 16384 B
    ushort_t* vT  = (ushort_t*)(U + 32768);    // 17408 B [64 d][136 m]
    // GEMM staging (aliases attn buffers): A buf i at U+i*8192,
    // B buf i at U+16384+i*12288.

    const int t = threadIdx.x;
    const int lane = t & 63;
    const int wv = t >> 6;
    const int l16 = lane & 15;
    const int lg = lane >> 4;
    const int m0 = blockIdx.x * 128;
    const int wm = wv >> 2;   // 0..1  (M half)
    const int wn = wv & 3;    // 0..3  (N quarter)
    // per-wave scratch aliased onto this wave's private qsm/ksm rows
    ushort_t* psw = ksm + wv * 1024;   // 256 needed of 1024
    ushort_t* olw = qsm + wv * 1024;   // 1024 needed

    // A slice: 128 rows x 32 K (8192 B = 512 x 16B), 1 unit/thread
    auto stageA = [&](int buf, int kb) {
        ushort_t* dst = (ushort_t*)(U + buf * 8192);
        int row = t >> 2, slot = t & 3;
        const ushort_t* src = xn + (size_t)(m0 + row) * 512 + kb * 32 + ((slot ^ ((row >> 2) & 3)) << 3);
        gload16(src, dst + t * 8);
    };
    // B slice: 192 rows x 32 K (12288 B = 768 x 16B), 1.5 units/thread
    auto stageB = [&](int buf, int kb, int h) {
        ushort_t* dst = (ushort_t*)(U + 16384 + buf * 12288);
        {
            int row = t >> 2, slot = t & 3;
            int wrow = (row >> 6) * 512 + h * 64 + (row & 63);
            const ushort_t* src = wq + (size_t)wrow * 512 + kb * 32 + ((slot ^ ((row >> 2) & 3)) << 3);
            gload16(src, dst + t * 8);
        }
        if (t < 256) {
            int u = t + 512;
            int row = u >> 2, slot = u & 3;
            int wrow = (row >> 6) * 512 + h * 64 + (row & 63);
            const ushort_t* src = wq + (size_t)wrow * 512 + kb * 32 + ((slot ^ ((row >> 2) & 3)) << 3);
            gload16(src, dst + u * 8);
        }
    };

    for (int h = 0; h < 8; ++h) {
        __syncthreads();                     // attn of h-1 done before re-alias
        stageA(0, 0); stageB(0, 0, h);
        __syncthreads();                     // staged data visible

        f32x4 acc[4][3];
        #pragma unroll
        for (int a1 = 0; a1 < 4; ++a1)
            #pragma unroll
            for (int a2 = 0; a2 < 3; ++a2)
                acc[a1][a2] = (f32x4){0.f, 0.f, 0.f, 0.f};

        for (int kb = 0; kb < 16; ++kb) {
            int cur = kb & 1;
            if (kb < 15) { stageA(cur ^ 1, kb + 1); stageB(cur ^ 1, kb + 1, h); }
            const ushort_t* Ac = (const ushort_t*)(U + cur * 8192);
            const ushort_t* Bc = (const ushort_t*)(U + 16384 + cur * 12288);
            s16x8 af[4], bf[3];
            #pragma unroll
            for (int mf = 0; mf < 4; ++mf) {
                int row = wm * 64 + mf * 16 + l16;
                af[mf] = *(const s16x8*)&Ac[row * 32 + ((lg ^ ((row >> 2) & 3)) << 3)];
            }
            #pragma unroll
            for (int nf = 0; nf < 3; ++nf) {
                int nrow = wn * 48 + nf * 16 + l16;
                bf[nf] = *(const s16x8*)&Bc[nrow * 32 + ((lg ^ ((nrow >> 2) & 3)) << 3)];
            }
            #pragma unroll
            for (int mf = 0; mf < 4; ++mf)
                #pragma unroll
                for (int nf = 0; nf < 3; ++nf)
                    acc[mf][nf] = __builtin_amdgcn_mfma_f32_16x16x32_bf16(af[mf], bf[nf], acc[mf][nf], 0, 0, 0);
            __syncthreads();
        }

        // C-write: q/k swizzled [m][d], V transposed [d][m]
        #pragma unroll
        for (int mf = 0; mf < 4; ++mf) {
            int mbase = wm * 64 + mf * 16 + lg * 4;
            #pragma unroll
            for (int nf = 0; nf < 3; ++nf) {
                int nn = wn * 48 + nf * 16 + l16;
                int seg = nn >> 6;
                int d = nn & 63;
                if (seg == 2) {
                    union { s16x4 v; ushort_t a[4]; } pk;
                    #pragma unroll
                    for (int r = 0; r < 4; ++r) pk.a[r] = f2bf(acc[mf][nf][r]);
                    *(s16x4*)&vT[d * 136 + mbase] = pk.v;
                } else {
                    ushort_t* dst = seg ? ksm : qsm;
                    #pragma unroll
                    for (int r = 0; r < 4; ++r) {
                        int m = mbase + r;
                        dst[m * 64 + (d ^ ((m & 7) << 3))] = f2bf(acc[mf][nf][r]);
                    }
                }
            }
        }
        __syncthreads();

        // ---- attention: wave wv handles sequence wv (16 rows) ----
        {
            int arow = wv * 16 + l16;
            int sw = (arow & 7) << 4;
            f32x4 sacc = (f32x4){0.f, 0.f, 0.f, 0.f};
            #pragma unroll
            for (int kk = 0; kk < 2; ++kk) {
                int off = kk * 64 + lg * 16;
                s16x8 ka = *(const s16x8*)&ksm[arow * 64 + ((off ^ sw) >> 1)];
                s16x8 qb = *(const s16x8*)&qsm[arow * 64 + ((off ^ sw) >> 1)];
                sacc = __builtin_amdgcn_mfma_f32_16x16x32_bf16(ka, qb, sacc, 0, 0, 0);
            }
            // lane holds S[j][i]: i = l16, j = lg*4+r
            const float* rbp = rb + l16 * 64 + lg * 4;
            float p[4];
            float mx = -1e30f;
            #pragma unroll
            for (int r = 0; r < 4; ++r) {
                p[r] = sacc[r] * 0.125f + rbp[r];
                mx = fmaxf(mx, p[r]);
            }
            mx = fmaxf(mx, __shfl_xor(mx, 16));
            mx = fmaxf(mx, __shfl_xor(mx, 32));
            float sum = 0.f;
            #pragma unroll
            for (int r = 0; r < 4; ++r) { p[r] = __expf(p[r] - mx); sum += p[r]; }
            sum += __shfl_xor(sum, 16);
            sum += __shfl_xor(sum, 32);
            float inv = 1.f / sum;
            {
                union { s16x4 v; ushort_t a[4]; } pk;
                #pragma unroll
                for (int r = 0; r < 4; ++r) pk.a[r] = f2bf(p[r] * inv);
                *(s16x4*)&psw[l16 * 16 + lg * 4] = pk.v;   // P[i][j]
            }
            asm volatile("s_waitcnt lgkmcnt(0)" ::: "memory");
            // PV: A = P rows i (j padded to 32 with zeros), B = vT rows d
            s16x8 ap = (s16x8){0, 0, 0, 0, 0, 0, 0, 0};
            if (lg < 2) ap = *(const s16x8*)&psw[l16 * 16 + lg * 8];
            int jj = (lg < 2) ? lg * 8 : 0;
            f32x4 ov[4];
            #pragma unroll
            for (int ff = 0; ff < 4; ++ff) {
                int d = ff * 16 + l16;
                s16x8 bv = *(const s16x8*)&vT[d * 136 + wv * 16 + jj];
                ov[ff] = __builtin_amdgcn_mfma_f32_16x16x32_bf16(ap, bv, (f32x4){0.f, 0.f, 0.f, 0.f}, 0, 0, 0);
            }
            // stage output through this wave's private LDS rows for 16B stores
            #pragma unroll
            for (int ff = 0; ff < 4; ++ff)
                #pragma unroll
                for (int r = 0; r < 4; ++r)
                    olw[(lg * 4 + r) * 64 + ff * 16 + l16] = f2bf(ov[ff][r]);
            asm volatile("s_waitcnt lgkmcnt(0)" ::: "memory");
            {
                int i2 = lane >> 2;
                int c2 = (lane & 3) * 16;
                s16x8 w0 = *(const s16x8*)&olw[i2 * 64 + c2];
                s16x8 w1 = *(const s16x8*)&olw[i2 * 64 + c2 + 8];
                ushort_t* op = att + (size_t)(m0 + wv * 16 + i2) * 512 + h * 64 + c2;
                *(s16x8*)op = w0;
                *(s16x8*)(op + 8) = w1;
            }
        }
    }
}

// ---------------- K3: proj GEMM + bias + residual + transpose-out ----------------
// block = (b, h, f-quad, n-half): M=128 rows (32 w x 4 f), N=256, K=512.
// 512 threads, 48 KB LDS, acc[4][4] -> 2 blocks/CU.
__global__ __launch_bounds__(512) void k_proj_out(
        const ushort_t* __restrict__ att, const ushort_t* __restrict__ wp,
        const float* __restrict__ bp, const float* __restrict__ x,
        float* __restrict__ out) {
    __shared__ __align__(16) char U[49152];   // A: 2x8192, B: 2x16384
    int bid = blockIdx.x;
    int nh = bid & 1;
    int fq = (bid >> 1) & 3;
    int h = (bid >> 3) & 31;
    int b = bid >> 8;
    const int n0 = nh * 256;
    const int t = threadIdx.x;
    const int lane = t & 63;
    const int wv = t >> 6;
    const int l16 = lane & 15;
    const int lg = lane >> 4;
    const int wm = wv >> 2;   // 0..1
    const int wn = wv & 3;    // 0..3
    size_t attbase = ((size_t)(b * 32 + h) * 32) * 16 + fq * 4;  // + w*16 + fl

    auto stA = [&](int buf, int ks) {
        int row = t >> 2, slot = t & 3;
        int w = row & 31, fl = row >> 5;
        const ushort_t* src = att + (attbase + (size_t)w * 16 + fl) * 512 + ks * 32 + ((slot ^ ((row >> 2) & 3)) << 3);
        gload16(src, (ushort_t*)(U + buf * 8192) + t * 8);
    };
    auto stB = [&](int buf, int ks) {
        #pragma unroll
        for (int i = 0; i < 2; ++i) {
            int u = t + i * 512;      // 1024 units (256 rows x 4 slots)
            int row = u >> 2, slot = u & 3;
            const ushort_t* src = wp + (size_t)(n0 + row) * 512 + ks * 32 + ((slot ^ ((row >> 2) & 3)) << 3);
            gload16(src, (ushort_t*)(U + 16384 + buf * 16384) + u * 8);
        }
    };

    f32x4 acc[4][4];
    #pragma unroll
    for (int m = 0; m < 4; ++m)
        #pragma unroll
        for (int n = 0; n < 4; ++n)
            acc[m][n] = (f32x4){0.f, 0.f, 0.f, 0.f};

    stA(0, 0); stB(0, 0);
    __syncthreads();
    for (int ks = 0; ks < 16; ++ks) {
        int cur = ks & 1;
        if (ks < 15) { stA(cur ^ 1, ks + 1); stB(cur ^ 1, ks + 1); }
        s16x8 af[4], bf[4];
        #pragma unroll
        for (int mf = 0; mf < 4; ++mf) {
            int row = wm * 64 + mf * 16 + l16;
            af[mf] = *(const s16x8*)((ushort_t*)(U + cur * 8192) + row * 32 + ((lg ^ ((row >> 2) & 3)) << 3));
        }
        #pragma unroll
        for (int nf = 0; nf < 4; ++nf) {
            int nrow = wn * 64 + nf * 16 + l16;
            bf[nf] = *(const s16x8*)((ushort_t*)(U + 16384 + cur * 16384) + nrow * 32 + ((lg ^ ((nrow >> 2) & 3)) << 3));
        }
        #pragma unroll
        for (int mf = 0; mf < 4; ++mf)
            #pragma unroll
            for (int nf = 0; nf < 4; ++nf)
                acc[mf][nf] = __builtin_amdgcn_mfma_f32_16x16x32_bf16(bf[nf], af[mf], acc[mf][nf], 0, 0, 0);
        __syncthreads();
    }

    // epilogue: direct stores, bias + residual fused (D: col l16 = M, row lg*4+r = N)
    size_t obase = (size_t)b * SB + (size_t)(fq * 4) * SF + h * 32;
    #pragma unroll
    for (int mf = 0; mf < 4; ++mf) {
        int m = wm * 64 + mf * 16 + l16;
        int w = m & 31, fl = m >> 5;
        size_t base_m = obase + (size_t)fl * SF + w;
        #pragma unroll
        for (int nf = 0; nf < 4; ++nf) {
            int col0 = n0 + wn * 64 + nf * 16 + lg * 4;
            #pragma unroll
            for (int r = 0; r < 4; ++r) {
                int col = col0 + r;
                size_t a = base_m + (size_t)col * SC;
                out[a] = acc[mf][nf][r] + bp[col] + x[a];
            }
        }
    }
}

extern "C" void kernel_launch(void* const* d_in, const int* in_sizes, int n_in,
                              void* d_out, int out_size, void* d_ws, size_t ws_size,
                              hipStream_t stream) {
    const float* x     = (const float*)d_in[0];
    const float* wqkv  = (const float*)d_in[1];
    const float* wproj = (const float*)d_in[2];
    const float* bproj = (const float*)d_in[3];
    const float* rb    = (const float*)d_in[4];
    const float* lng   = (const float*)d_in[5];
    const float* lnb   = (const float*)d_in[6];
    float* out = (float*)d_out;
    char* ws = (char*)d_ws;
    ushort_t* xn   = (ushort_t*)(ws);                  // 64 MB
    ushort_t* att  = (ushort_t*)(ws + 67108864);       // 64 MB
    ushort_t* wq16 = (ushort_t*)(ws + 134217728);      // 1.5 MB
    ushort_t* wp16 = (ushort_t*)(ws + 135790592);      // 0.5 MB

    k_cvt<<<3072, 256, 0, stream>>>(wqkv, 1536 * 512, wproj, 512 * 512, wq16, wp16);
    k_ln_transpose<<<2048, 256, 0, stream>>>(x, lng, lnb, xn);
    k_qkv_attn<<<512, 512, 0, stream>>>(xn, wq16, rb, att);
    k_proj_out<<<1024, 512, 0, stream>>>(att, wp16, bproj, x, out);
}

// Round 7
// 320.267 us; speedup vs baseline: 2.0533x; 1.1345x over previous
//
#include <hip/hip_runtime.h>

typedef unsigned short ushort_t;
typedef __attribute__((ext_vector_type(4))) float f32x4;
typedef __attribute__((ext_vector_type(8))) short s16x8;
typedef __attribute__((ext_vector_type(4))) short s16x4;

#define SB 8388608   // x batch stride (512*16*32*32)
#define SC 16384     // x channel stride (16*32*32)
#define SF 1024      // x frame stride (32*32)

static __device__ __forceinline__ float bf2f(ushort_t u) {
    union { float f; unsigned int i; } x; x.i = ((unsigned int)u) << 16; return x.f;
}
static __device__ __forceinline__ ushort_t f2bf(float f) {
    union { float f; unsigned int i; } x; x.f = f;
    unsigned int u = x.i;
    unsigned int r = (u + 0x7FFFu + ((u >> 16) & 1u)) >> 16;
    return (ushort_t)r;
}

static __device__ __forceinline__ void gload16(const void* g, void* l) {
    __builtin_amdgcn_global_load_lds(
        (const __attribute__((address_space(1))) unsigned int*)g,
        (__attribute__((address_space(3))) unsigned int*)l, 16, 0, 0);
}

// raw barrier: no implicit vmcnt(0) drain (that's the point)
static __device__ __forceinline__ void wg_barrier() {
    asm volatile("" ::: "memory");
    __builtin_amdgcn_s_barrier();
    asm volatile("" ::: "memory");
}

// ---------------- K0: convert weights to bf16 ----------------
__global__ void k_cvt(const float* __restrict__ a, int n1,
                      const float* __restrict__ b, int n2,
                      ushort_t* __restrict__ o1, ushort_t* __restrict__ o2) {
    int i = blockIdx.x * blockDim.x + threadIdx.x;
    if (i < n1) o1[i] = f2bf(a[i]);
    if (i < n2) o2[i] = f2bf(b[i]);
}

// ---------------- K1: LayerNorm + transpose -> xn (65536 x 512) bf16 ----------------
__global__ __launch_bounds__(256) void k_ln_transpose(
        const float* __restrict__ x, const float* __restrict__ g,
        const float* __restrict__ bta, ushort_t* __restrict__ xn) {
    __shared__ float tile[32 * 513];
    __shared__ float gg[512];
    __shared__ float bb[512];
    int bid = blockIdx.x;
    int b = bid >> 9;
    int f = (bid >> 5) & 15;
    int h = bid & 31;
    int t = threadIdx.x;
    for (int c = t; c < 512; c += 256) { gg[c] = g[c]; bb[c] = bta[c]; }
    const float* xp = x + (size_t)b * SB + (size_t)f * SF + h * 32;
    int wq4 = (t & 7) * 4;
    int c0 = t >> 3;
    for (int it = 0; it < 16; ++it) {
        int c = c0 + it * 32;
        f32x4 v = *(const f32x4*)(xp + (size_t)c * SC + wq4);
        tile[(wq4 + 0) * 513 + c] = v[0];
        tile[(wq4 + 1) * 513 + c] = v[1];
        tile[(wq4 + 2) * 513 + c] = v[2];
        tile[(wq4 + 3) * 513 + c] = v[3];
    }
    __syncthreads();
    int lane = t & 63;
    int wave = t >> 6;
    for (int wi = 0; wi < 8; ++wi) {
        int ww = wave * 8 + wi;
        float s = 0.f, s2 = 0.f;
        #pragma unroll
        for (int j = 0; j < 8; ++j) {
            float v = tile[ww * 513 + lane + j * 64];
            s += v; s2 += v * v;
        }
        #pragma unroll
        for (int off = 32; off; off >>= 1) { s += __shfl_xor(s, off); s2 += __shfl_xor(s2, off); }
        float mean = s * (1.f / 512.f);
        float var = s2 * (1.f / 512.f) - mean * mean;
        float rstd = rsqrtf(var + 1e-5f);
        size_t row = ((size_t)((b * 32 + h) * 32 + ww)) * 16 + f;
        ushort_t* op = xn + row * 512 + lane * 8;
        union { ushort_t a[8]; s16x8 v; } u;
        #pragma unroll
        for (int j = 0; j < 8; ++j) {
            int c = lane * 8 + j;
            float v = tile[ww * 513 + c];
            u.a[j] = f2bf((v - mean) * rstd * gg[c] + bb[c]);
        }
        *(s16x8*)op = u.v;
    }
}

// ---------------- K2: fused QKV GEMM + attention ----------------
// block = 8 sequences (128 rows), 512 threads (8 waves). BK=64, 3-deep
// staging ring with 2-ahead prefetch + counted vmcnt (no drain-0 in loop).
// LDS 120 KB; attention buffers alias the ring. 1 block/CU (reg-limited),
// latency hidden by ILP, not TLP.
__global__ __launch_bounds__(512) void k_qkv_attn(
        const ushort_t* __restrict__ xn, const ushort_t* __restrict__ wq,
        const float* __restrict__ rb, ushort_t* __restrict__ att) {
    __shared__ __align__(16) char U[122880];
    // staging ring: A buf i @ U + i*16384 (i<3); B buf i @ U + 49152 + i*24576
    // attention layout (aliases ring):
    ushort_t* qsm = (ushort_t*)(U);            // 16384 B [128 m][64 d] swz
    ushort_t* ksm = (ushort_t*)(U + 16384);    // 16384 B
    ushort_t* vT  = (ushort_t*)(U + 32768);    // 17408 B [64 d][136 m]

    const int t = threadIdx.x;
    const int lane = t & 63;
    const int wv = t >> 6;
    const int l16 = lane & 15;
    const int lg = lane >> 4;
    const int m0 = blockIdx.x * 128;
    const int wm = wv >> 2;   // 0..1  (M half)
    const int wn = wv & 3;    // 0..3  (N quarter)
    ushort_t* psw = ksm + wv * 1024;   // per-wave P scratch
    ushort_t* olw = qsm + wv * 1024;   // per-wave out-stage scratch

    // A K-slice: 128 rows x 64 K (16384 B = 1024 x 16B), 2 loads/thread
    auto stageA = [&](int buf, int kb) {
        ushort_t* dst = (ushort_t*)(U + buf * 16384);
        #pragma unroll
        for (int it = 0; it < 2; ++it) {
            int f = t + it * 512;
            int row = f >> 3, slot = f & 7;
            const ushort_t* src = xn + (size_t)(m0 + row) * 512 + kb * 64 + ((slot ^ (row & 7)) << 3);
            gload16(src, dst + f * 8);
        }
    };
    // B K-slice: 192 rows x 64 K (24576 B = 1536 x 16B), 3 loads/thread
    auto stageB = [&](int buf, int kb, int h) {
        ushort_t* dst = (ushort_t*)(U + 49152 + buf * 24576);
        #pragma unroll
        for (int it = 0; it < 3; ++it) {
            int f = t + it * 512;
            int brow = f >> 3, slot = f & 7;
            int wrow = (brow >> 6) * 512 + h * 64 + (brow & 63);
            const ushort_t* src = wq + (size_t)wrow * 512 + kb * 64 + ((slot ^ (brow & 7)) << 3);
            gload16(src, dst + f * 8);
        }
    };

    for (int h = 0; h < 8; ++h) {
        __syncthreads();                     // attn of h-1 fully done before ring reuse
        stageA(0, 0); stageB(0, 0, h);       // kb=0  (5 loads)
        stageA(1, 1); stageB(1, 1, h);       // kb=1  (5 loads) -> 10 in flight

        f32x4 acc[4][3];
        #pragma unroll
        for (int a1 = 0; a1 < 4; ++a1)
            #pragma unroll
            for (int a2 = 0; a2 < 3; ++a2)
                acc[a1][a2] = (f32x4){0.f, 0.f, 0.f, 0.f};

        for (int kb = 0; kb < 8; ++kb) {
            int cur = kb % 3;
            if (kb < 6) {
                stageA((kb + 2) % 3, kb + 2);
                stageB((kb + 2) % 3, kb + 2, h);
                asm volatile("s_waitcnt vmcnt(10)" ::: "memory");  // stage(kb) done
            } else if (kb == 6) {
                asm volatile("s_waitcnt vmcnt(5)" ::: "memory");
            } else {
                asm volatile("s_waitcnt vmcnt(0)" ::: "memory");
            }
            wg_barrier();                    // all waves' stage(kb) visible
            const ushort_t* Ac = (const ushort_t*)(U + cur * 16384);
            const ushort_t* Bc = (const ushort_t*)(U + 49152 + cur * 24576);
            #pragma unroll
            for (int kk = 0; kk < 2; ++kk) {
                int koff = kk * 64 + lg * 16;   // byte offset within 128B row
                s16x8 af[4], bf[3];
                #pragma unroll
                for (int mf = 0; mf < 4; ++mf) {
                    int row = wm * 64 + mf * 16 + l16;
                    af[mf] = *(const s16x8*)&Ac[row * 64 + ((koff ^ ((row & 7) << 4)) >> 1)];
                }
                #pragma unroll
                for (int nf = 0; nf < 3; ++nf) {
                    int nrow = wn * 48 + nf * 16 + l16;
                    bf[nf] = *(const s16x8*)&Bc[nrow * 64 + ((koff ^ ((nrow & 7) << 4)) >> 1)];
                }
                #pragma unroll
                for (int mf = 0; mf < 4; ++mf)
                    #pragma unroll
                    for (int nf = 0; nf < 3; ++nf)
                        acc[mf][nf] = __builtin_amdgcn_mfma_f32_16x16x32_bf16(af[mf], bf[nf], acc[mf][nf], 0, 0, 0);
            }
            wg_barrier();                    // readers done before ring slot reuse
        }

        // C-write: q/k swizzled [m][d], V transposed [d][m] (aliases ring)
        #pragma unroll
        for (int mf = 0; mf < 4; ++mf) {
            int mbase = wm * 64 + mf * 16 + lg * 4;
            #pragma unroll
            for (int nf = 0; nf < 3; ++nf) {
                int nn = wn * 48 + nf * 16 + l16;
                int seg = nn >> 6;
                int d = nn & 63;
                if (seg == 2) {
                    union { s16x4 v; ushort_t a[4]; } pk;
                    #pragma unroll
                    for (int r = 0; r < 4; ++r) pk.a[r] = f2bf(acc[mf][nf][r]);
                    *(s16x4*)&vT[d * 136 + mbase] = pk.v;
                } else {
                    ushort_t* dst = seg ? ksm : qsm;
                    #pragma unroll
                    for (int r = 0; r < 4; ++r) {
                        int m = mbase + r;
                        dst[m * 64 + (d ^ ((m & 7) << 3))] = f2bf(acc[mf][nf][r]);
                    }
                }
            }
        }
        __syncthreads();

        // ---- attention: wave wv handles sequence wv (16 rows) ----
        {
            int arow = wv * 16 + l16;
            int sw = (arow & 7) << 4;
            f32x4 sacc = (f32x4){0.f, 0.f, 0.f, 0.f};
            #pragma unroll
            for (int kk = 0; kk < 2; ++kk) {
                int off = kk * 64 + lg * 16;
                s16x8 ka = *(const s16x8*)&ksm[arow * 64 + ((off ^ sw) >> 1)];
                s16x8 qb = *(const s16x8*)&qsm[arow * 64 + ((off ^ sw) >> 1)];
                sacc = __builtin_amdgcn_mfma_f32_16x16x32_bf16(ka, qb, sacc, 0, 0, 0);
            }
            // lane holds S[j][i]: i = l16, j = lg*4+r
            const float* rbp = rb + l16 * 64 + lg * 4;
            float p[4];
            float mx = -1e30f;
            #pragma unroll
            for (int r = 0; r < 4; ++r) {
                p[r] = sacc[r] * 0.125f + rbp[r];
                mx = fmaxf(mx, p[r]);
            }
            mx = fmaxf(mx, __shfl_xor(mx, 16));
            mx = fmaxf(mx, __shfl_xor(mx, 32));
            float sum = 0.f;
            #pragma unroll
            for (int r = 0; r < 4; ++r) { p[r] = __expf(p[r] - mx); sum += p[r]; }
            sum += __shfl_xor(sum, 16);
            sum += __shfl_xor(sum, 32);
            float inv = 1.f / sum;
            {
                union { s16x4 v; ushort_t a[4]; } pk;
                #pragma unroll
                for (int r = 0; r < 4; ++r) pk.a[r] = f2bf(p[r] * inv);
                *(s16x4*)&psw[l16 * 16 + lg * 4] = pk.v;   // P[i][j]
            }
            asm volatile("s_waitcnt lgkmcnt(0)" ::: "memory");
            // PV: A = P rows i (j padded to 32 with zeros), B = vT rows d
            s16x8 ap = (s16x8){0, 0, 0, 0, 0, 0, 0, 0};
            if (lg < 2) ap = *(const s16x8*)&psw[l16 * 16 + lg * 8];
            int jj = (lg < 2) ? lg * 8 : 0;
            f32x4 ov[4];
            #pragma unroll
            for (int ff = 0; ff < 4; ++ff) {
                int d = ff * 16 + l16;
                s16x8 bv = *(const s16x8*)&vT[d * 136 + wv * 16 + jj];
                ov[ff] = __builtin_amdgcn_mfma_f32_16x16x32_bf16(ap, bv, (f32x4){0.f, 0.f, 0.f, 0.f}, 0, 0, 0);
            }
            // stage output through this wave's private LDS rows for 16B stores
            #pragma unroll
            for (int ff = 0; ff < 4; ++ff)
                #pragma unroll
                for (int r = 0; r < 4; ++r)
                    olw[(lg * 4 + r) * 64 + ff * 16 + l16] = f2bf(ov[ff][r]);
            asm volatile("s_waitcnt lgkmcnt(0)" ::: "memory");
            {
                int i2 = lane >> 2;
                int c2 = (lane & 3) * 16;
                s16x8 w0 = *(const s16x8*)&olw[i2 * 64 + c2];
                s16x8 w1 = *(const s16x8*)&olw[i2 * 64 + c2 + 8];
                ushort_t* op = att + (size_t)(m0 + wv * 16 + i2) * 512 + h * 64 + c2;
                *(s16x8*)op = w0;
                *(s16x8*)(op + 8) = w1;
            }
        }
    }
}

// ---------------- K3: proj GEMM + bias + residual + transpose-out ----------------
// block = (b, h, f-quad, n-half): M=128 rows, N=256, K=512. 512 threads.
// BK=32, 3-deep ring + counted vmcnt. LDS 72 KB.
__global__ __launch_bounds__(512) void k_proj_out(
        const ushort_t* __restrict__ att, const ushort_t* __restrict__ wp,
        const float* __restrict__ bp, const float* __restrict__ x,
        float* __restrict__ out) {
    __shared__ __align__(16) char U[73728];   // A: 3x8192 @0, B: 3x16384 @24576
    int bid = blockIdx.x;
    int nh = bid & 1;
    int fq = (bid >> 1) & 3;
    int h = (bid >> 3) & 31;
    int b = bid >> 8;
    const int n0 = nh * 256;
    const int t = threadIdx.x;
    const int lane = t & 63;
    const int wv = t >> 6;
    const int l16 = lane & 15;
    const int lg = lane >> 4;
    const int wm = wv >> 2;   // 0..1
    const int wn = wv & 3;    // 0..3
    size_t attbase = ((size_t)(b * 32 + h) * 32) * 16 + fq * 4;  // + w*16 + fl

    auto stA = [&](int buf, int ks) {
        int row = t >> 2, slot = t & 3;
        int w = row & 31, fl = row >> 5;
        const ushort_t* src = att + (attbase + (size_t)w * 16 + fl) * 512 + ks * 32 + ((slot ^ ((row >> 2) & 3)) << 3);
        gload16(src, (ushort_t*)(U + buf * 8192) + t * 8);
    };
    auto stB = [&](int buf, int ks) {
        #pragma unroll
        for (int i = 0; i < 2; ++i) {
            int u = t + i * 512;      // 1024 units (256 rows x 4 slots)
            int row = u >> 2, slot = u & 3;
            const ushort_t* src = wp + (size_t)(n0 + row) * 512 + ks * 32 + ((slot ^ ((row >> 2) & 3)) << 3);
            gload16(src, (ushort_t*)(U + 24576 + buf * 16384) + u * 8);
        }
    };

    f32x4 acc[4][4];
    #pragma unroll
    for (int m = 0; m < 4; ++m)
        #pragma unroll
        for (int n = 0; n < 4; ++n)
            acc[m][n] = (f32x4){0.f, 0.f, 0.f, 0.f};

    stA(0, 0); stB(0, 0);    // 3 loads
    stA(1, 1); stB(1, 1);    // 3 loads -> 6 in flight
    for (int ks = 0; ks < 16; ++ks) {
        int cur = ks % 3;
        if (ks < 14) {
            stA((ks + 2) % 3, ks + 2);
            stB((ks + 2) % 3, ks + 2);
            asm volatile("s_waitcnt vmcnt(6)" ::: "memory");
        } else if (ks == 14) {
            asm volatile("s_waitcnt vmcnt(3)" ::: "memory");
        } else {
            asm volatile("s_waitcnt vmcnt(0)" ::: "memory");
        }
        wg_barrier();
        s16x8 af[4], bf[4];
        #pragma unroll
        for (int mf = 0; mf < 4; ++mf) {
            int row = wm * 64 + mf * 16 + l16;
            af[mf] = *(const s16x8*)((ushort_t*)(U + cur * 8192) + row * 32 + ((lg ^ ((row >> 2) & 3)) << 3));
        }
        #pragma unroll
        for (int nf = 0; nf < 4; ++nf) {
            int nrow = wn * 64 + nf * 16 + l16;
            bf[nf] = *(const s16x8*)((ushort_t*)(U + 24576 + cur * 16384) + nrow * 32 + ((lg ^ ((nrow >> 2) & 3)) << 3));
        }
        #pragma unroll
        for (int mf = 0; mf < 4; ++mf)
            #pragma unroll
            for (int nf = 0; nf < 4; ++nf)
                acc[mf][nf] = __builtin_amdgcn_mfma_f32_16x16x32_bf16(bf[nf], af[mf], acc[mf][nf], 0, 0, 0);
        wg_barrier();
    }

    // epilogue: direct stores, bias + residual fused (D: col l16 = M, row lg*4+r = N)
    size_t obase = (size_t)b * SB + (size_t)(fq * 4) * SF + h * 32;
    #pragma unroll
    for (int mf = 0; mf < 4; ++mf) {
        int m = wm * 64 + mf * 16 + l16;
        int w = m & 31, fl = m >> 5;
        size_t base_m = obase + (size_t)fl * SF + w;
        #pragma unroll
        for (int nf = 0; nf < 4; ++nf) {
            int col0 = n0 + wn * 64 + nf * 16 + lg * 4;
            #pragma unroll
            for (int r = 0; r < 4; ++r) {
                int col = col0 + r;
                size_t a = base_m + (size_t)col * SC;
                out[a] = acc[mf][nf][r] + bp[col] + x[a];
            }
        }
    }
}

extern "C" void kernel_launch(void* const* d_in, const int* in_sizes, int n_in,
                              void* d_out, int out_size, void* d_ws, size_t ws_size,
                              hipStream_t stream) {
    const float* x     = (const float*)d_in[0];
    const float* wqkv  = (const float*)d_in[1];
    const float* wproj = (const float*)d_in[2];
    const float* bproj = (const float*)d_in[3];
    const float* rb    = (const float*)d_in[4];
    const float* lng   = (const float*)d_in[5];
    const float* lnb   = (const float*)d_in[6];
    float* out = (float*)d_out;
    char* ws = (char*)d_ws;
    ushort_t* xn   = (ushort_t*)(ws);                  // 64 MB
    ushort_t* att  = (ushort_t*)(ws + 67108864);       // 64 MB
    ushort_t* wq16 = (ushort_t*)(ws + 134217728);      // 1.5 MB
    ushort_t* wp16 = (ushort_t*)(ws + 135790592);      // 0.5 MB

    k_cvt<<<3072, 256, 0, stream>>>(wqkv, 1536 * 512, wproj, 512 * 512, wq16, wp16);
    k_ln_transpose<<<2048, 256, 0, stream>>>(x, lng, lnb, xn);
    k_qkv_attn<<<512, 512, 0, stream>>>(xn, wq16, rb, att);
    k_proj_out<<<1024, 512, 0, stream>>>(att, wp16, bproj, x, out);
}